// Round 1
// baseline (302.981 us; speedup 1.0000x reference)
//
#include <hip/hip_runtime.h>
#include <hip/hip_bf16.h>
#include <cstdint>
#include <cstddef>

// Problem constants
constexpr int T_TOK = 4096;   // B*S
constexpr int H_DIM = 1024;
constexpr int E_NUM = 8;
constexpr int I_DIM = 1024;
constexpr int F2    = 2048;   // 2*I
constexpr float ALPHA = 1.702f;
constexpr float LIMIT = 7.0f;
constexpr int MAXTILES = 136; // >= sum(ceil(cnt_e/64)) worst case (135)

using u16    = unsigned short;
using bf16x8 = __attribute__((ext_vector_type(8))) __bf16;
using s16x8  = __attribute__((ext_vector_type(8))) short;
using f32x4  = __attribute__((ext_vector_type(4))) float;

// Workspace layout (bytes)
constexpr size_t WS_W1T  = 0;                        // [E][2][I][H] bf16 : 33,554,432
constexpr size_t WS_W2T  = 33554432;                 // [E][H][I]   bf16 : 16,777,216
constexpr size_t WS_ACT  = 50331648;                 // [8192][I]   bf16 : 16,777,216
constexpr size_t WS_ETOK = 67108864;                 // [E][T] int       :    131,072
constexpr size_t WS_EW   = 67239936;                 // [E][T] float     :    131,072
constexpr size_t WS_CNT  = 67371008;                 // [E] int
constexpr size_t WS_ROWB = 67371040;                 // [E] int
constexpr size_t WS_ASGN = 67371072;                 // [MAXTILES] int
constexpr size_t WS_NEED = 67371072 + MAXTILES * 4;

__device__ __forceinline__ u16 f2bf(float f) {
    union { float f; unsigned u; } v; v.f = f;
    return (u16)((v.u + 0x7FFFu + ((v.u >> 16) & 1u)) >> 16);   // RNE
}

__device__ __forceinline__ s16x8 pack8(float4 a, float4 b) {
    s16x8 r;
    r[0] = (short)f2bf(a.x); r[1] = (short)f2bf(a.y);
    r[2] = (short)f2bf(a.z); r[3] = (short)f2bf(a.w);
    r[4] = (short)f2bf(b.x); r[5] = (short)f2bf(b.y);
    r[6] = (short)f2bf(b.z); r[7] = (short)f2bf(b.w);
    return r;
}

// ---------------------------------------------------------------------------
// Transpose gate_up_proj [E][H][2I] fp32 -> [E][2][I][H] bf16 (de-interleave)
// ---------------------------------------------------------------------------
__global__ __launch_bounds__(256) void k_transpose_w1(const float* __restrict__ in,
                                                      u16* __restrict__ out) {
    __shared__ float tile[64][65];
    const int e = blockIdx.z, c0 = blockIdx.x * 64, h0 = blockIdx.y * 64;
    const int tid = threadIdx.x;
    const float* src = in + ((size_t)e * H_DIM + h0) * F2 + c0;
#pragma unroll
    for (int i = 0; i < 4; ++i) {
        int r = (tid >> 4) + i * 16, c = (tid & 15) * 4;
        float4 v = *(const float4*)(src + (size_t)r * F2 + c);
        tile[r][c] = v.x; tile[r][c + 1] = v.y; tile[r][c + 2] = v.z; tile[r][c + 3] = v.w;
    }
    __syncthreads();
    const int c = tid >> 2, hseg = (tid & 3) * 16;
    const int g = c & 1;
    const int f = (c0 + c) >> 1;
    u16* dst = out + (((size_t)e * 2 + g) * I_DIM + f) * H_DIM + h0 + hseg;
    s16x8 o0, o1;
#pragma unroll
    for (int j = 0; j < 8; ++j) o0[j] = (short)f2bf(tile[hseg + j][c]);
#pragma unroll
    for (int j = 0; j < 8; ++j) o1[j] = (short)f2bf(tile[hseg + 8 + j][c]);
    *(s16x8*)dst = o0;
    *(s16x8*)(dst + 8) = o1;
}

// ---------------------------------------------------------------------------
// Transpose down_proj [E][I][H] fp32 -> [E][H][I] bf16
// ---------------------------------------------------------------------------
__global__ __launch_bounds__(256) void k_transpose_w2(const float* __restrict__ in,
                                                      u16* __restrict__ out) {
    __shared__ float tile[64][65];
    const int e = blockIdx.z, h0 = blockIdx.x * 64, i0 = blockIdx.y * 64;
    const int tid = threadIdx.x;
    const float* src = in + ((size_t)e * I_DIM + i0) * H_DIM + h0;
#pragma unroll
    for (int i = 0; i < 4; ++i) {
        int r = (tid >> 4) + i * 16, c = (tid & 15) * 4;
        float4 v = *(const float4*)(src + (size_t)r * H_DIM + c);
        tile[r][c] = v.x; tile[r][c + 1] = v.y; tile[r][c + 2] = v.z; tile[r][c + 3] = v.w;
    }
    __syncthreads();
    const int c = tid >> 2, iseg = (tid & 3) * 16;
    u16* dst = out + ((size_t)e * H_DIM + h0 + c) * I_DIM + i0 + iseg;
    s16x8 o0, o1;
#pragma unroll
    for (int j = 0; j < 8; ++j) o0[j] = (short)f2bf(tile[iseg + j][c]);
#pragma unroll
    for (int j = 0; j < 8; ++j) o1[j] = (short)f2bf(tile[iseg + 8 + j][c]);
    *(s16x8*)dst = o0;
    *(s16x8*)(dst + 8) = o1;
}

// ---------------------------------------------------------------------------
// Router: fp32 logits, top-2 (jax tie semantics: lower index wins), softmax,
// scatter (token, weight) into per-expert lists. One wave per token.
// ---------------------------------------------------------------------------
__global__ __launch_bounds__(256) void k_router(const float* __restrict__ x,
                                                const float* __restrict__ rw,
                                                int* __restrict__ cnt,
                                                int* __restrict__ ent_tok,
                                                float* __restrict__ ent_w) {
    const int wave = threadIdx.x >> 6, lane = threadIdx.x & 63;
    const int t = blockIdx.x * 4 + wave;
    const float* xr = x + (size_t)t * H_DIM;
    float acc[E_NUM];
#pragma unroll
    for (int e = 0; e < E_NUM; ++e) acc[e] = 0.f;
    for (int h = lane; h < H_DIM; h += 64) {
        float xv = xr[h];
        const float* r = rw + h * E_NUM;
#pragma unroll
        for (int e = 0; e < E_NUM; ++e) acc[e] += xv * r[e];
    }
#pragma unroll
    for (int e = 0; e < E_NUM; ++e) {
        float v = acc[e];
#pragma unroll
        for (int o = 32; o > 0; o >>= 1) v += __shfl_down(v, o);
        acc[e] = v;
    }
    if (lane == 0) {
        int e0 = 0; float v0 = acc[0];
#pragma unroll
        for (int e = 1; e < E_NUM; ++e) if (acc[e] > v0) { v0 = acc[e]; e0 = e; }
        int e1 = -1; float v1 = -3.4e38f;
#pragma unroll
        for (int e = 0; e < E_NUM; ++e) if (e != e0 && acc[e] > v1) { v1 = acc[e]; e1 = e; }
        float ew = expf(v1 - v0);
        float inv = 1.f / (1.f + ew);
        float w0 = inv, w1 = ew * inv;
        int p0 = atomicAdd(&cnt[e0], 1);
        ent_tok[e0 * T_TOK + p0] = t; ent_w[e0 * T_TOK + p0] = w0;
        int p1 = atomicAdd(&cnt[e1], 1);
        ent_tok[e1 * T_TOK + p1] = t; ent_w[e1 * T_TOK + p1] = w1;
    }
}

// ---------------------------------------------------------------------------
// Schedule: counts -> row bases + fixed-size tile assignment table.
// ---------------------------------------------------------------------------
__global__ void k_schedule(const int* __restrict__ cnt, int* __restrict__ rowbase,
                           int* __restrict__ assign) {
    if (threadIdx.x == 0) {
        int rb = 0, na = 0;
        for (int e = 0; e < E_NUM; ++e) {
            rowbase[e] = rb;
            int nt = (cnt[e] + 63) >> 6;
            for (int m = 0; m < nt; ++m) assign[na++] = (e << 16) | m;
            rb += cnt[e];
        }
        for (; na < MAXTILES; ++na) assign[na] = -1;
    }
}

// ---------------------------------------------------------------------------
// GEMM1: act[row][j] = glu(x_row . Wg[:,j] + bg) * (clip(x_row . Wu[:,j] + bu)+1)
// Block: 64 entries x 64 act cols (gate+up = 128 B-rows). 4 waves, 2x2.
// ---------------------------------------------------------------------------
__global__ __launch_bounds__(256) void k_gemm1(
    const float* __restrict__ x, const u16* __restrict__ w1t,
    const float* __restrict__ bias, const int* __restrict__ ent_tok,
    const int* __restrict__ cnt, const int* __restrict__ rowbase,
    const int* __restrict__ assign, u16* __restrict__ act) {
    const int a = assign[blockIdx.x];
    if (a < 0) return;
    const int e = a >> 16, mt = a & 0xffff;
    const int j0 = blockIdx.y * 64;
    const int cs = cnt[e], r0 = mt * 64;
    __shared__ __align__(16) u16 As[64 * 32];
    __shared__ __align__(16) u16 Bs[128 * 32];
    const int tid = threadIdx.x;
    // A staging: thread -> (row, k-octet)
    const int ar = tid >> 2, ak = (tid & 3) * 8;
    const int aent = r0 + ar;
    const int atok = (aent < cs) ? ent_tok[e * T_TOK + aent] : 0;
    const float* ax = x + (size_t)atok * H_DIM + ak;
    const int agrp = ((ak >> 3) ^ (ar & 3)) * 8;
    // B staging: thread -> (n-row of [gate64|up64], 16-k half)
    const int bn = tid >> 1, bk = (tid & 1) * 16;
    const int bg = bn >> 6, bj = j0 + (bn & 63);
    const u16* bx = w1t + (((size_t)e * 2 + bg) * I_DIM + bj) * H_DIM + bk;
    const int bgrp0 = (((bk >> 3)    ) ^ (bn & 3)) * 8;
    const int bgrp1 = (((bk >> 3) + 1) ^ (bn & 3)) * 8;
    // wave decomposition: 2(M) x 2(N-act)
    const int lane = tid & 63, wave = tid >> 6;
    const int wm = wave >> 1, wn = wave & 1;
    const int lcol = lane & 15, lk = lane >> 4;

    f32x4 accg[2][2], accu[2][2];
    const f32x4 z = {0.f, 0.f, 0.f, 0.f};
#pragma unroll
    for (int mi = 0; mi < 2; ++mi)
#pragma unroll
        for (int fj = 0; fj < 2; ++fj) { accg[mi][fj] = z; accu[mi][fj] = z; }

    for (int kb = 0; kb < H_DIM; kb += 32) {
        __syncthreads();
        float4 f0 = *(const float4*)(ax + kb);
        float4 f1 = *(const float4*)(ax + kb + 4);
        *(s16x8*)&As[ar * 32 + agrp] = pack8(f0, f1);
        s16x8 b0 = *(const s16x8*)(bx + kb);
        s16x8 b1 = *(const s16x8*)(bx + kb + 8);
        *(s16x8*)&Bs[bn * 32 + bgrp0] = b0;
        *(s16x8*)&Bs[bn * 32 + bgrp1] = b1;
        __syncthreads();
        bf16x8 af[2], bgf[2], buf_[2];
#pragma unroll
        for (int mi = 0; mi < 2; ++mi) {
            int rr = wm * 32 + mi * 16 + lcol;
            af[mi] = *(const bf16x8*)&As[rr * 32 + ((lk ^ (rr & 3)) * 8)];
        }
#pragma unroll
        for (int fj = 0; fj < 2; ++fj) {
            int ng = wn * 32 + fj * 16 + lcol;
            bgf[fj]  = *(const bf16x8*)&Bs[ng * 32 + ((lk ^ (ng & 3)) * 8)];
            int nu = 64 + ng;
            buf_[fj] = *(const bf16x8*)&Bs[nu * 32 + ((lk ^ (nu & 3)) * 8)];
        }
#pragma unroll
        for (int mi = 0; mi < 2; ++mi)
#pragma unroll
            for (int fj = 0; fj < 2; ++fj) {
                accg[mi][fj] = __builtin_amdgcn_mfma_f32_16x16x32_bf16(af[mi], bgf[fj],  accg[mi][fj], 0, 0, 0);
                accu[mi][fj] = __builtin_amdgcn_mfma_f32_16x16x32_bf16(af[mi], buf_[fj], accu[mi][fj], 0, 0, 0);
            }
    }
    // epilogue: clamp + GLU, store bf16 act
    const int rbase = rowbase[e];
#pragma unroll
    for (int mi = 0; mi < 2; ++mi) {
#pragma unroll
        for (int fj = 0; fj < 2; ++fj) {
            int col = j0 + wn * 32 + fj * 16 + lcol;
            float biasg = bias[e * F2 + 2 * col];
            float biasu = bias[e * F2 + 2 * col + 1];
#pragma unroll
            for (int rg = 0; rg < 4; ++rg) {
                int r = wm * 32 + mi * 16 + lk * 4 + rg;
                if (r0 + r < cs) {
                    float gv = accg[mi][fj][rg] + biasg;
                    float uv = accu[mi][fj][rg] + biasu;
                    gv = fminf(gv, LIMIT);
                    uv = fminf(fmaxf(uv, -LIMIT), LIMIT);
                    float glu = gv / (1.f + expf(-ALPHA * gv));
                    float av = (uv + 1.f) * glu;
                    act[(size_t)(rbase + r0 + r) * I_DIM + col] = f2bf(av);
                }
            }
        }
    }
}

// ---------------------------------------------------------------------------
// GEMM2: out[tok] += w_ent * (act_row . W2[:,h] + b2). Block 64 x 128.
// ---------------------------------------------------------------------------
__global__ __launch_bounds__(256) void k_gemm2(
    const u16* __restrict__ act, const u16* __restrict__ w2t,
    const float* __restrict__ bias, const int* __restrict__ ent_tok,
    const float* __restrict__ ent_w, const int* __restrict__ cnt,
    const int* __restrict__ rowbase, const int* __restrict__ assign,
    float* __restrict__ out) {
    const int a = assign[blockIdx.x];
    if (a < 0) return;
    const int e = a >> 16, mt = a & 0xffff;
    const int n0 = blockIdx.y * 128;
    const int cs = cnt[e], r0 = mt * 64, rbase = rowbase[e];
    __shared__ __align__(16) u16 As[64 * 32];
    __shared__ __align__(16) u16 Bs[128 * 32];
    const int tid = threadIdx.x;
    const int ar = tid >> 2, ak = (tid & 3) * 8;
    int arow = rbase + r0 + ar;
    if (arow > 2 * T_TOK - 1) arow = 2 * T_TOK - 1;   // pad rows of last tile
    const u16* ax = act + (size_t)arow * I_DIM + ak;
    const int agrp = ((ak >> 3) ^ (ar & 3)) * 8;
    const int bn = tid >> 1, bk = (tid & 1) * 16;
    const u16* bx = w2t + ((size_t)e * H_DIM + n0 + bn) * I_DIM + bk;
    const int bgrp0 = (((bk >> 3)    ) ^ (bn & 3)) * 8;
    const int bgrp1 = (((bk >> 3) + 1) ^ (bn & 3)) * 8;
    const int lane = tid & 63, wave = tid >> 6;
    const int wm = wave >> 1, wn = wave & 1;
    const int lcol = lane & 15, lk = lane >> 4;

    f32x4 acc[2][4];
    const f32x4 z = {0.f, 0.f, 0.f, 0.f};
#pragma unroll
    for (int mi = 0; mi < 2; ++mi)
#pragma unroll
        for (int fj = 0; fj < 4; ++fj) acc[mi][fj] = z;

    for (int kb = 0; kb < I_DIM; kb += 32) {
        __syncthreads();
        s16x8 av = *(const s16x8*)(ax + kb);
        *(s16x8*)&As[ar * 32 + agrp] = av;
        s16x8 b0 = *(const s16x8*)(bx + kb);
        s16x8 b1 = *(const s16x8*)(bx + kb + 8);
        *(s16x8*)&Bs[bn * 32 + bgrp0] = b0;
        *(s16x8*)&Bs[bn * 32 + bgrp1] = b1;
        __syncthreads();
        bf16x8 af[2], bf_[4];
#pragma unroll
        for (int mi = 0; mi < 2; ++mi) {
            int rr = wm * 32 + mi * 16 + lcol;
            af[mi] = *(const bf16x8*)&As[rr * 32 + ((lk ^ (rr & 3)) * 8)];
        }
#pragma unroll
        for (int fj = 0; fj < 4; ++fj) {
            int nn = wn * 64 + fj * 16 + lcol;
            bf_[fj] = *(const bf16x8*)&Bs[nn * 32 + ((lk ^ (nn & 3)) * 8)];
        }
#pragma unroll
        for (int mi = 0; mi < 2; ++mi)
#pragma unroll
            for (int fj = 0; fj < 4; ++fj)
                acc[mi][fj] = __builtin_amdgcn_mfma_f32_16x16x32_bf16(af[mi], bf_[fj], acc[mi][fj], 0, 0, 0);
    }
#pragma unroll
    for (int mi = 0; mi < 2; ++mi) {
#pragma unroll
        for (int fj = 0; fj < 4; ++fj) {
            int col = n0 + wn * 64 + fj * 16 + lcol;
            float bv = bias[e * H_DIM + col];
#pragma unroll
            for (int rg = 0; rg < 4; ++rg) {
                int r = wm * 32 + mi * 16 + lk * 4 + rg;
                if (r0 + r < cs) {
                    int ent = e * T_TOK + r0 + r;
                    float w = ent_w[ent];
                    int tok = ent_tok[ent];
                    atomicAdd(&out[(size_t)tok * H_DIM + col], w * (acc[mi][fj][rg] + bv));
                }
            }
        }
    }
}

// ---------------------------------------------------------------------------
extern "C" void kernel_launch(void* const* d_in, const int* in_sizes, int n_in,
                              void* d_out, int out_size, void* d_ws, size_t ws_size,
                              hipStream_t stream) {
    const float* x   = (const float*)d_in[0];
    const float* rw  = (const float*)d_in[1];
    const float* w1  = (const float*)d_in[2];
    const float* b1  = (const float*)d_in[3];
    const float* w2  = (const float*)d_in[4];
    const float* b2  = (const float*)d_in[5];
    float* out = (float*)d_out;
    char* ws = (char*)d_ws;

    if (ws_size < WS_NEED) return;  // signals as pure-zero/poison output

    u16*   W1T  = (u16*)(ws + WS_W1T);
    u16*   W2T  = (u16*)(ws + WS_W2T);
    u16*   ACT  = (u16*)(ws + WS_ACT);
    int*   ETOK = (int*)(ws + WS_ETOK);
    float* EW   = (float*)(ws + WS_EW);
    int*   CNT  = (int*)(ws + WS_CNT);
    int*   ROWB = (int*)(ws + WS_ROWB);
    int*   ASGN = (int*)(ws + WS_ASGN);

    hipMemsetAsync(CNT, 0, E_NUM * sizeof(int), stream);
    hipMemsetAsync(out, 0, (size_t)T_TOK * H_DIM * sizeof(float), stream);

    k_transpose_w1<<<dim3(32, 16, 8), 256, 0, stream>>>(w1, W1T);
    k_transpose_w2<<<dim3(16, 16, 8), 256, 0, stream>>>(w2, W2T);
    k_router<<<T_TOK / 4, 256, 0, stream>>>(x, rw, CNT, ETOK, EW);
    k_schedule<<<1, 64, 0, stream>>>(CNT, ROWB, ASGN);
    k_gemm1<<<dim3(MAXTILES, 16), 256, 0, stream>>>(x, W1T, b1, ETOK, CNT, ROWB, ASGN, ACT);
    k_gemm2<<<dim3(MAXTILES, 8), 256, 0, stream>>>(ACT, W2T, b2, ETOK, EW, CNT, ROWB, ASGN, out);
}

// Round 2
// 212.960 us; speedup vs baseline: 1.4227x; 1.4227x over previous
//
#include <hip/hip_runtime.h>
#include <hip/hip_bf16.h>
#include <cstdint>
#include <cstddef>

// Problem constants
constexpr int T_TOK = 4096;   // B*S
constexpr int H_DIM = 1024;
constexpr int E_NUM = 8;
constexpr int I_DIM = 1024;
constexpr int F2    = 2048;   // 2*I
constexpr float ALPHA = 1.702f;
constexpr float LIMIT = 7.0f;
constexpr int MAXTILES = 136; // >= sum(ceil(cnt_e/64)) worst case (135)

using u16    = unsigned short;
using bf16x8 = __attribute__((ext_vector_type(8))) __bf16;
using s16x8  = __attribute__((ext_vector_type(8))) short;
using f32x4  = __attribute__((ext_vector_type(4))) float;

// Workspace layout (bytes)
constexpr size_t WS_W1T  = 0;                        // [E][2][I][H] bf16 : 33,554,432
constexpr size_t WS_W2T  = 33554432;                 // [E][H][I]   bf16 : 16,777,216
constexpr size_t WS_ACT  = 50331648;                 // [8192][I]   bf16 : 16,777,216
constexpr size_t WS_ETOK = 67108864;                 // [E][T] int       :    131,072
constexpr size_t WS_EW   = 67239936;                 // [E][T] float     :    131,072
constexpr size_t WS_CNT  = 67371008;                 // [E] int
constexpr size_t WS_ROWB = 67371040;                 // [E] int
constexpr size_t WS_ASGN = 67371072;                 // [MAXTILES] int
constexpr size_t WS_TOPE = 67371072 + 1024;          // [T] int (packed e0|e1<<8)
constexpr size_t WS_TOPW = WS_TOPE + T_TOK * 4;      // [T] float2
constexpr size_t WS_NEED = WS_TOPW + T_TOK * 8;

__device__ __forceinline__ u16 f2bf(float f) {
    union { float f; unsigned u; } v; v.f = f;
    return (u16)((v.u + 0x7FFFu + ((v.u >> 16) & 1u)) >> 16);   // RNE
}

__device__ __forceinline__ s16x8 pack8(float4 a, float4 b) {
    s16x8 r;
    r[0] = (short)f2bf(a.x); r[1] = (short)f2bf(a.y);
    r[2] = (short)f2bf(a.z); r[3] = (short)f2bf(a.w);
    r[4] = (short)f2bf(b.x); r[5] = (short)f2bf(b.y);
    r[6] = (short)f2bf(b.z); r[7] = (short)f2bf(b.w);
    return r;
}

// ---------------------------------------------------------------------------
// Transpose gate_up_proj [E][H][2I] fp32 -> [E][2][I][H] bf16 (de-interleave)
// ---------------------------------------------------------------------------
__global__ __launch_bounds__(256) void k_transpose_w1(const float* __restrict__ in,
                                                      u16* __restrict__ out) {
    __shared__ float tile[64][65];
    const int e = blockIdx.z, c0 = blockIdx.x * 64, h0 = blockIdx.y * 64;
    const int tid = threadIdx.x;
    const float* src = in + ((size_t)e * H_DIM + h0) * F2 + c0;
#pragma unroll
    for (int i = 0; i < 4; ++i) {
        int r = (tid >> 4) + i * 16, c = (tid & 15) * 4;
        float4 v = *(const float4*)(src + (size_t)r * F2 + c);
        tile[r][c] = v.x; tile[r][c + 1] = v.y; tile[r][c + 2] = v.z; tile[r][c + 3] = v.w;
    }
    __syncthreads();
    const int c = tid >> 2, hseg = (tid & 3) * 16;
    const int g = c & 1;
    const int f = (c0 + c) >> 1;
    u16* dst = out + (((size_t)e * 2 + g) * I_DIM + f) * H_DIM + h0 + hseg;
    s16x8 o0, o1;
#pragma unroll
    for (int j = 0; j < 8; ++j) o0[j] = (short)f2bf(tile[hseg + j][c]);
#pragma unroll
    for (int j = 0; j < 8; ++j) o1[j] = (short)f2bf(tile[hseg + 8 + j][c]);
    *(s16x8*)dst = o0;
    *(s16x8*)(dst + 8) = o1;
}

// ---------------------------------------------------------------------------
// Transpose down_proj [E][I][H] fp32 -> [E][H][I] bf16
// ---------------------------------------------------------------------------
__global__ __launch_bounds__(256) void k_transpose_w2(const float* __restrict__ in,
                                                      u16* __restrict__ out) {
    __shared__ float tile[64][65];
    const int e = blockIdx.z, h0 = blockIdx.x * 64, i0 = blockIdx.y * 64;
    const int tid = threadIdx.x;
    const float* src = in + ((size_t)e * I_DIM + i0) * H_DIM + h0;
#pragma unroll
    for (int i = 0; i < 4; ++i) {
        int r = (tid >> 4) + i * 16, c = (tid & 15) * 4;
        float4 v = *(const float4*)(src + (size_t)r * H_DIM + c);
        tile[r][c] = v.x; tile[r][c + 1] = v.y; tile[r][c + 2] = v.z; tile[r][c + 3] = v.w;
    }
    __syncthreads();
    const int c = tid >> 2, iseg = (tid & 3) * 16;
    u16* dst = out + ((size_t)e * H_DIM + h0 + c) * I_DIM + i0 + iseg;
    s16x8 o0, o1;
#pragma unroll
    for (int j = 0; j < 8; ++j) o0[j] = (short)f2bf(tile[iseg + j][c]);
#pragma unroll
    for (int j = 0; j < 8; ++j) o1[j] = (short)f2bf(tile[iseg + 8 + j][c]);
    *(s16x8*)dst = o0;
    *(s16x8*)(dst + 8) = o1;
}

// ---------------------------------------------------------------------------
// Router phase 1: fp32 logits, top-2 (jax tie semantics: lower index wins),
// softmax. One wave per token. NO atomics — writes packed (e0,e1) + (w0,w1).
// ---------------------------------------------------------------------------
__global__ __launch_bounds__(256) void k_router_top2(const float* __restrict__ x,
                                                     const float* __restrict__ rw,
                                                     int* __restrict__ tope,
                                                     float2* __restrict__ topw) {
    const int wave = threadIdx.x >> 6, lane = threadIdx.x & 63;
    const int t = blockIdx.x * 4 + wave;
    const float* xr = x + (size_t)t * H_DIM;
    float acc[E_NUM];
#pragma unroll
    for (int e = 0; e < E_NUM; ++e) acc[e] = 0.f;
    for (int h = lane; h < H_DIM; h += 64) {
        float xv = xr[h];
        const float* r = rw + h * E_NUM;
#pragma unroll
        for (int e = 0; e < E_NUM; ++e) acc[e] += xv * r[e];
    }
#pragma unroll
    for (int e = 0; e < E_NUM; ++e) {
        float v = acc[e];
#pragma unroll
        for (int o = 32; o > 0; o >>= 1) v += __shfl_down(v, o);
        acc[e] = v;
    }
    if (lane == 0) {
        int e0 = 0; float v0 = acc[0];
#pragma unroll
        for (int e = 1; e < E_NUM; ++e) if (acc[e] > v0) { v0 = acc[e]; e0 = e; }
        int e1 = -1; float v1 = -3.4e38f;
#pragma unroll
        for (int e = 0; e < E_NUM; ++e) if (e != e0 && acc[e] > v1) { v1 = acc[e]; e1 = e; }
        float ew = expf(v1 - v0);
        float inv = 1.f / (1.f + ew);
        tope[t] = e0 | (e1 << 8);
        topw[t] = make_float2(inv, ew * inv);
    }
}

// ---------------------------------------------------------------------------
// Router phase 2: block-aggregated scatter. 16 blocks x 256 tokens.
// LDS histogram -> 1 global atomic per (block, expert) -> scatter.
// ---------------------------------------------------------------------------
__global__ __launch_bounds__(256) void k_router_scatter(const int* __restrict__ tope,
                                                        const float2* __restrict__ topw,
                                                        int* __restrict__ cnt,
                                                        int* __restrict__ ent_tok,
                                                        float* __restrict__ ent_w) {
    __shared__ int lcnt[E_NUM];
    __shared__ int gbase[E_NUM];
    const int tid = threadIdx.x;
    const int t = blockIdx.x * 256 + tid;
    if (tid < E_NUM) lcnt[tid] = 0;
    __syncthreads();
    const int pk = tope[t];
    const float2 w = topw[t];
    const int e0 = pk & 0xff, e1 = pk >> 8;
    const int o0 = atomicAdd(&lcnt[e0], 1);
    const int o1 = atomicAdd(&lcnt[e1], 1);
    __syncthreads();
    if (tid < E_NUM) gbase[tid] = atomicAdd(&cnt[tid], lcnt[tid]);
    __syncthreads();
    const int p0 = gbase[e0] + o0;
    const int p1 = gbase[e1] + o1;
    ent_tok[e0 * T_TOK + p0] = t; ent_w[e0 * T_TOK + p0] = w.x;
    ent_tok[e1 * T_TOK + p1] = t; ent_w[e1 * T_TOK + p1] = w.y;
}

// ---------------------------------------------------------------------------
// Schedule: counts -> row bases + fixed-size tile assignment table.
// ---------------------------------------------------------------------------
__global__ void k_schedule(const int* __restrict__ cnt, int* __restrict__ rowbase,
                           int* __restrict__ assign) {
    if (threadIdx.x == 0) {
        int rb = 0, na = 0;
        for (int e = 0; e < E_NUM; ++e) {
            rowbase[e] = rb;
            int nt = (cnt[e] + 63) >> 6;
            for (int m = 0; m < nt; ++m) assign[na++] = (e << 16) | m;
            rb += cnt[e];
        }
        for (; na < MAXTILES; ++na) assign[na] = -1;
    }
}

// ---------------------------------------------------------------------------
// GEMM1: act[row][j] = glu(x_row . Wg[:,j] + bg) * (clip(x_row . Wu[:,j] + bu)+1)
// Block: 64 entries x 64 act cols (gate+up = 128 B-rows). 4 waves, 2x2.
// ---------------------------------------------------------------------------
__global__ __launch_bounds__(256) void k_gemm1(
    const float* __restrict__ x, const u16* __restrict__ w1t,
    const float* __restrict__ bias, const int* __restrict__ ent_tok,
    const int* __restrict__ cnt, const int* __restrict__ rowbase,
    const int* __restrict__ assign, u16* __restrict__ act) {
    const int a = assign[blockIdx.x];
    if (a < 0) return;
    const int e = a >> 16, mt = a & 0xffff;
    const int j0 = blockIdx.y * 64;
    const int cs = cnt[e], r0 = mt * 64;
    __shared__ __align__(16) u16 As[64 * 32];
    __shared__ __align__(16) u16 Bs[128 * 32];
    const int tid = threadIdx.x;
    // A staging: thread -> (row, k-octet)
    const int ar = tid >> 2, ak = (tid & 3) * 8;
    const int aent = r0 + ar;
    const int atok = (aent < cs) ? ent_tok[e * T_TOK + aent] : 0;
    const float* ax = x + (size_t)atok * H_DIM + ak;
    const int agrp = ((ak >> 3) ^ (ar & 3)) * 8;
    // B staging: thread -> (n-row of [gate64|up64], 16-k half)
    const int bn = tid >> 1, bk = (tid & 1) * 16;
    const int bg = bn >> 6, bj = j0 + (bn & 63);
    const u16* bx = w1t + (((size_t)e * 2 + bg) * I_DIM + bj) * H_DIM + bk;
    const int bgrp0 = (((bk >> 3)    ) ^ (bn & 3)) * 8;
    const int bgrp1 = (((bk >> 3) + 1) ^ (bn & 3)) * 8;
    // wave decomposition: 2(M) x 2(N-act)
    const int lane = tid & 63, wave = tid >> 6;
    const int wm = wave >> 1, wn = wave & 1;
    const int lcol = lane & 15, lk = lane >> 4;

    f32x4 accg[2][2], accu[2][2];
    const f32x4 z = {0.f, 0.f, 0.f, 0.f};
#pragma unroll
    for (int mi = 0; mi < 2; ++mi)
#pragma unroll
        for (int fj = 0; fj < 2; ++fj) { accg[mi][fj] = z; accu[mi][fj] = z; }

    for (int kb = 0; kb < H_DIM; kb += 32) {
        __syncthreads();
        float4 f0 = *(const float4*)(ax + kb);
        float4 f1 = *(const float4*)(ax + kb + 4);
        *(s16x8*)&As[ar * 32 + agrp] = pack8(f0, f1);
        s16x8 b0 = *(const s16x8*)(bx + kb);
        s16x8 b1 = *(const s16x8*)(bx + kb + 8);
        *(s16x8*)&Bs[bn * 32 + bgrp0] = b0;
        *(s16x8*)&Bs[bn * 32 + bgrp1] = b1;
        __syncthreads();
        bf16x8 af[2], bgf[2], buf_[2];
#pragma unroll
        for (int mi = 0; mi < 2; ++mi) {
            int rr = wm * 32 + mi * 16 + lcol;
            af[mi] = *(const bf16x8*)&As[rr * 32 + ((lk ^ (rr & 3)) * 8)];
        }
#pragma unroll
        for (int fj = 0; fj < 2; ++fj) {
            int ng = wn * 32 + fj * 16 + lcol;
            bgf[fj]  = *(const bf16x8*)&Bs[ng * 32 + ((lk ^ (ng & 3)) * 8)];
            int nu = 64 + ng;
            buf_[fj] = *(const bf16x8*)&Bs[nu * 32 + ((lk ^ (nu & 3)) * 8)];
        }
#pragma unroll
        for (int mi = 0; mi < 2; ++mi)
#pragma unroll
            for (int fj = 0; fj < 2; ++fj) {
                accg[mi][fj] = __builtin_amdgcn_mfma_f32_16x16x32_bf16(af[mi], bgf[fj],  accg[mi][fj], 0, 0, 0);
                accu[mi][fj] = __builtin_amdgcn_mfma_f32_16x16x32_bf16(af[mi], buf_[fj], accu[mi][fj], 0, 0, 0);
            }
    }
    // epilogue: clamp + GLU, store bf16 act
    const int rbase = rowbase[e];
#pragma unroll
    for (int mi = 0; mi < 2; ++mi) {
#pragma unroll
        for (int fj = 0; fj < 2; ++fj) {
            int col = j0 + wn * 32 + fj * 16 + lcol;
            float biasg = bias[e * F2 + 2 * col];
            float biasu = bias[e * F2 + 2 * col + 1];
#pragma unroll
            for (int rg = 0; rg < 4; ++rg) {
                int r = wm * 32 + mi * 16 + lk * 4 + rg;
                if (r0 + r < cs) {
                    float gv = accg[mi][fj][rg] + biasg;
                    float uv = accu[mi][fj][rg] + biasu;
                    gv = fminf(gv, LIMIT);
                    uv = fminf(fmaxf(uv, -LIMIT), LIMIT);
                    float glu = gv / (1.f + expf(-ALPHA * gv));
                    float av = (uv + 1.f) * glu;
                    act[(size_t)(rbase + r0 + r) * I_DIM + col] = f2bf(av);
                }
            }
        }
    }
}

// ---------------------------------------------------------------------------
// GEMM2: out[tok] += w_ent * (act_row . W2[:,h] + b2). Block 64 x 128.
// ---------------------------------------------------------------------------
__global__ __launch_bounds__(256) void k_gemm2(
    const u16* __restrict__ act, const u16* __restrict__ w2t,
    const float* __restrict__ bias, const int* __restrict__ ent_tok,
    const float* __restrict__ ent_w, const int* __restrict__ cnt,
    const int* __restrict__ rowbase, const int* __restrict__ assign,
    float* __restrict__ out) {
    const int a = assign[blockIdx.x];
    if (a < 0) return;
    const int e = a >> 16, mt = a & 0xffff;
    const int n0 = blockIdx.y * 128;
    const int cs = cnt[e], r0 = mt * 64, rbase = rowbase[e];
    __shared__ __align__(16) u16 As[64 * 32];
    __shared__ __align__(16) u16 Bs[128 * 32];
    const int tid = threadIdx.x;
    const int ar = tid >> 2, ak = (tid & 3) * 8;
    int arow = rbase + r0 + ar;
    if (arow > 2 * T_TOK - 1) arow = 2 * T_TOK - 1;   // pad rows of last tile
    const u16* ax = act + (size_t)arow * I_DIM + ak;
    const int agrp = ((ak >> 3) ^ (ar & 3)) * 8;
    const int bn = tid >> 1, bk = (tid & 1) * 16;
    const u16* bx = w2t + ((size_t)e * H_DIM + n0 + bn) * I_DIM + bk;
    const int bgrp0 = (((bk >> 3)    ) ^ (bn & 3)) * 8;
    const int bgrp1 = (((bk >> 3) + 1) ^ (bn & 3)) * 8;
    const int lane = tid & 63, wave = tid >> 6;
    const int wm = wave >> 1, wn = wave & 1;
    const int lcol = lane & 15, lk = lane >> 4;

    f32x4 acc[2][4];
    const f32x4 z = {0.f, 0.f, 0.f, 0.f};
#pragma unroll
    for (int mi = 0; mi < 2; ++mi)
#pragma unroll
        for (int fj = 0; fj < 4; ++fj) acc[mi][fj] = z;

    for (int kb = 0; kb < I_DIM; kb += 32) {
        __syncthreads();
        s16x8 av = *(const s16x8*)(ax + kb);
        *(s16x8*)&As[ar * 32 + agrp] = av;
        s16x8 b0 = *(const s16x8*)(bx + kb);
        s16x8 b1 = *(const s16x8*)(bx + kb + 8);
        *(s16x8*)&Bs[bn * 32 + bgrp0] = b0;
        *(s16x8*)&Bs[bn * 32 + bgrp1] = b1;
        __syncthreads();
        bf16x8 af[2], bf_[4];
#pragma unroll
        for (int mi = 0; mi < 2; ++mi) {
            int rr = wm * 32 + mi * 16 + lcol;
            af[mi] = *(const bf16x8*)&As[rr * 32 + ((lk ^ (rr & 3)) * 8)];
        }
#pragma unroll
        for (int fj = 0; fj < 4; ++fj) {
            int nn = wn * 64 + fj * 16 + lcol;
            bf_[fj] = *(const bf16x8*)&Bs[nn * 32 + ((lk ^ (nn & 3)) * 8)];
        }
#pragma unroll
        for (int mi = 0; mi < 2; ++mi)
#pragma unroll
            for (int fj = 0; fj < 4; ++fj)
                acc[mi][fj] = __builtin_amdgcn_mfma_f32_16x16x32_bf16(af[mi], bf_[fj], acc[mi][fj], 0, 0, 0);
    }
#pragma unroll
    for (int mi = 0; mi < 2; ++mi) {
#pragma unroll
        for (int fj = 0; fj < 4; ++fj) {
            int col = n0 + wn * 64 + fj * 16 + lcol;
            float bv = bias[e * H_DIM + col];
#pragma unroll
            for (int rg = 0; rg < 4; ++rg) {
                int r = wm * 32 + mi * 16 + lk * 4 + rg;
                if (r0 + r < cs) {
                    int ent = e * T_TOK + r0 + r;
                    float w = ent_w[ent];
                    int tok = ent_tok[ent];
                    atomicAdd(&out[(size_t)tok * H_DIM + col], w * (acc[mi][fj][rg] + bv));
                }
            }
        }
    }
}

// ---------------------------------------------------------------------------
extern "C" void kernel_launch(void* const* d_in, const int* in_sizes, int n_in,
                              void* d_out, int out_size, void* d_ws, size_t ws_size,
                              hipStream_t stream) {
    const float* x   = (const float*)d_in[0];
    const float* rw  = (const float*)d_in[1];
    const float* w1  = (const float*)d_in[2];
    const float* b1  = (const float*)d_in[3];
    const float* w2  = (const float*)d_in[4];
    const float* b2  = (const float*)d_in[5];
    float* out = (float*)d_out;
    char* ws = (char*)d_ws;

    if (ws_size < WS_NEED) return;

    u16*    W1T  = (u16*)(ws + WS_W1T);
    u16*    W2T  = (u16*)(ws + WS_W2T);
    u16*    ACT  = (u16*)(ws + WS_ACT);
    int*    ETOK = (int*)(ws + WS_ETOK);
    float*  EW   = (float*)(ws + WS_EW);
    int*    CNT  = (int*)(ws + WS_CNT);
    int*    ROWB = (int*)(ws + WS_ROWB);
    int*    ASGN = (int*)(ws + WS_ASGN);
    int*    TOPE = (int*)(ws + WS_TOPE);
    float2* TOPW = (float2*)(ws + WS_TOPW);

    hipMemsetAsync(CNT, 0, E_NUM * sizeof(int), stream);
    hipMemsetAsync(out, 0, (size_t)T_TOK * H_DIM * sizeof(float), stream);

    k_transpose_w1<<<dim3(32, 16, 8), 256, 0, stream>>>(w1, W1T);
    k_transpose_w2<<<dim3(16, 16, 8), 256, 0, stream>>>(w2, W2T);
    k_router_top2<<<T_TOK / 4, 256, 0, stream>>>(x, rw, TOPE, TOPW);
    k_router_scatter<<<T_TOK / 256, 256, 0, stream>>>(TOPE, TOPW, CNT, ETOK, EW);
    k_schedule<<<1, 64, 0, stream>>>(CNT, ROWB, ASGN);
    k_gemm1<<<dim3(MAXTILES, 16), 256, 0, stream>>>(x, W1T, b1, ETOK, CNT, ROWB, ASGN, ACT);
    k_gemm2<<<dim3(MAXTILES, 8), 256, 0, stream>>>(ACT, W2T, b2, ETOK, EW, CNT, ROWB, ASGN, out);
}